// Round 1
// baseline (1436.214 us; speedup 1.0000x reference)
//
#include <hip/hip_runtime.h>

// Problem constants (match reference)
constexpr int N  = 100000;   // nodes
constexpr int E  = 3200000;  // edges
constexpr int G  = 128;      // graphs
constexpr int H  = 64;       // hidden

// ---------------------------------------------------------------------------
// K1: in-degree counts (dst occurrences); self-loop added later as +1
__global__ __launch_bounds__(256) void k_count(const int* __restrict__ dst,
                                               int* __restrict__ cnt) {
    int e = blockIdx.x * 256 + threadIdx.x;
    if (e < E) atomicAdd(&cnt[dst[e]], 1);
}

// K2: dinv = rsqrt(deg), gx = x * dinv (pre-scaled 2-channel features)
__global__ __launch_bounds__(256) void k_dinv(const float* __restrict__ x,
                                              const int* __restrict__ cnt,
                                              float* __restrict__ dinv,
                                              float2* __restrict__ gx) {
    int v = blockIdx.x * 256 + threadIdx.x;
    if (v < N) {
        float d = rsqrtf((float)(cnt[v] + 1));
        dinv[v] = d;
        float2 xv = ((const float2*)x)[v];
        gx[v] = make_float2(xv.x * d, xv.y * d);
    }
}

// K3: single-block exclusive scan of cnt -> offs (and cursor copy).
// Each thread serially sums a contiguous segment; one block-level scan.
__global__ __launch_bounds__(1024) void k_scan(const int* __restrict__ cnt,
                                               int* __restrict__ offs,
                                               int* __restrict__ cursor) {
    constexpr int T = 1024;
    constexpr int PER = (N + T - 1) / T;  // 98
    int tid = threadIdx.x;
    int begin = tid * PER;
    int end = begin + PER; if (end > N) end = N;

    int total = 0;
    for (int i = begin; i < end; ++i) total += cnt[i];

    // block exclusive scan of per-thread totals
    __shared__ int wsum[16];
    int lane = tid & 63, wid = tid >> 6;
    int incl = total;
    #pragma unroll
    for (int off = 1; off < 64; off <<= 1) {
        int t = __shfl_up(incl, off);
        if (lane >= off) incl += t;
    }
    if (lane == 63) wsum[wid] = incl;
    __syncthreads();
    if (wid == 0 && lane < 16) {
        int w = wsum[lane];
        #pragma unroll
        for (int off = 1; off < 16; off <<= 1) {
            int t = __shfl_up(w, off);
            if (lane >= off) w += t;
        }
        wsum[lane] = w;  // inclusive over waves
    }
    __syncthreads();
    int waveBase = (wid == 0) ? 0 : wsum[wid - 1];
    int run = waveBase + (incl - total);  // exclusive prefix of this thread
    for (int i = begin; i < end; ++i) {
        offs[i] = run;
        cursor[i] = run;
        run += cnt[i];
    }
}

// K4: fill CSR (src indices grouped by dst)
__global__ __launch_bounds__(256) void k_fill(const int* __restrict__ src,
                                              const int* __restrict__ dst,
                                              int* __restrict__ cursor,
                                              int* __restrict__ csr) {
    int e = blockIdx.x * 256 + threadIdx.x;
    if (e < E) {
        int d = dst[e];
        int pos = atomicAdd(&cursor[d], 1);
        csr[pos] = src[e];
    }
}

// K5: layer-1 aggregation in 2-channel input space. 4 lanes per node.
// aggx[v] = dinv[v] * (sum_{s->v} gx[s] + gx[v])
__global__ __launch_bounds__(256) void k_agg1(const int* __restrict__ csr,
                                              const int* __restrict__ offs,
                                              const int* __restrict__ cnt,
                                              const float* __restrict__ dinv,
                                              const float2* __restrict__ gx,
                                              float2* __restrict__ aggx) {
    int t = blockIdx.x * 256 + threadIdx.x;
    int v = t >> 2, r = t & 3;
    if (v >= N) return;
    int start = offs[v], dg = cnt[v];
    float ax = 0.f, ay = 0.f;
    for (int i = r; i < dg; i += 4) {
        int s = csr[start + i];
        float2 g = gx[s];
        ax += g.x; ay += g.y;
    }
    ax += __shfl_xor(ax, 1); ay += __shfl_xor(ay, 1);
    ax += __shfl_xor(ax, 2); ay += __shfl_xor(ay, 2);
    if (r == 0) {
        float d = dinv[v];
        float2 g = gx[v];
        aggx[v] = make_float2(d * (ax + g.x), d * (ay + g.y));
    }
}

// K6: per-node MLP: t = relu(aggx @ W1 + b1)  (64-wide, lane j owns t_j)
//     g2 = (t @ W2) * dinv[v]                 (W2 column j in 64 VGPRs,
//                                              t_k broadcast via v_readlane)
__global__ __launch_bounds__(256) void k_mlp(const float2* __restrict__ aggx,
                                             const float* __restrict__ W1,
                                             const float* __restrict__ b1,
                                             const float* __restrict__ W2,
                                             const float* __restrict__ dinv,
                                             float* __restrict__ g2) {
    int lane = threadIdx.x & 63;
    int wave = (blockIdx.x * 256 + threadIdx.x) >> 6;
    int nw = gridDim.x * 4;

    float w2col[64];
    #pragma unroll
    for (int k = 0; k < 64; ++k) w2col[k] = W2[k * 64 + lane];
    float w10 = W1[lane], w11 = W1[64 + lane], bb = b1[lane];

    for (int v = wave; v < N; v += nw) {
        float2 a = aggx[v];
        float tt = fmaxf(fmaf(a.y, w11, fmaf(a.x, w10, bb)), 0.f);
        float a0 = 0.f, a1 = 0.f, a2 = 0.f, a3 = 0.f;
        #pragma unroll
        for (int k = 0; k < 64; k += 4) {
            float t0 = __int_as_float(__builtin_amdgcn_readlane(__float_as_int(tt), k + 0));
            float t1 = __int_as_float(__builtin_amdgcn_readlane(__float_as_int(tt), k + 1));
            float t2 = __int_as_float(__builtin_amdgcn_readlane(__float_as_int(tt), k + 2));
            float t3 = __int_as_float(__builtin_amdgcn_readlane(__float_as_int(tt), k + 3));
            a0 = fmaf(t0, w2col[k + 0], a0);
            a1 = fmaf(t1, w2col[k + 1], a1);
            a2 = fmaf(t2, w2col[k + 2], a2);
            a3 = fmaf(t3, w2col[k + 3], a3);
        }
        g2[(size_t)v * 64 + lane] = ((a0 + a1) + (a2 + a3)) * dinv[v];
    }
}

// K7: layer-2 aggregation (wave per node) + relu + fused mean-pool atomics
__global__ __launch_bounds__(256) void k_agg2(const int* __restrict__ csr,
                                              const int* __restrict__ offs,
                                              const int* __restrict__ cnt,
                                              const float* __restrict__ dinv,
                                              const float* __restrict__ b2,
                                              const float* __restrict__ g2,
                                              const int* __restrict__ batch,
                                              float* __restrict__ pooled,
                                              int* __restrict__ cntg) {
    int lane = threadIdx.x & 63;
    int v = (blockIdx.x * 256 + threadIdx.x) >> 6;
    if (v >= N) return;
    int start = offs[v], dg = cnt[v];
    float acc = g2[(size_t)v * 64 + lane];  // self-loop term
    int i = 0;
    for (; i + 3 < dg; i += 4) {
        int s0 = csr[start + i + 0];
        int s1 = csr[start + i + 1];
        int s2 = csr[start + i + 2];
        int s3 = csr[start + i + 3];
        float f0 = g2[(size_t)s0 * 64 + lane];
        float f1 = g2[(size_t)s1 * 64 + lane];
        float f2 = g2[(size_t)s2 * 64 + lane];
        float f3 = g2[(size_t)s3 * 64 + lane];
        acc += f0; acc += f1; acc += f2; acc += f3;
    }
    for (; i < dg; ++i) {
        int s = csr[start + i];
        acc += g2[(size_t)s * 64 + lane];
    }
    float o = fmaxf(fmaf(dinv[v], acc, b2[lane]), 0.f);
    int b = batch[v];
    atomicAdd(&pooled[b * 64 + lane], o);
    if (lane == 0) atomicAdd(&cntg[b], 1);
}

// K8: final: out[g] = (pooled[g]/max(cnt,1)) . Wfc + bfc
__global__ __launch_bounds__(64) void k_final(const float* __restrict__ pooled,
                                              const int* __restrict__ cntg,
                                              const float* __restrict__ Wfc,
                                              const float* __restrict__ bfc,
                                              float* __restrict__ out) {
    int g = blockIdx.x;
    int j = threadIdx.x;  // 64
    float c = fmaxf((float)cntg[g], 1.f);
    float p = (pooled[g * 64 + j] / c) * Wfc[j];
    #pragma unroll
    for (int off = 32; off >= 1; off >>= 1) p += __shfl_down(p, off);
    if (j == 0) out[g] = p + bfc[0];
}

// ---------------------------------------------------------------------------
extern "C" void kernel_launch(void* const* d_in, const int* in_sizes, int n_in,
                              void* d_out, int out_size, void* d_ws, size_t ws_size,
                              hipStream_t stream) {
    const float* x     = (const float*)d_in[0];
    const int*   edge  = (const int*)d_in[1];
    const int*   batch = (const int*)d_in[2];
    const float* W1    = (const float*)d_in[3];
    const float* b1    = (const float*)d_in[4];
    const float* W2    = (const float*)d_in[5];
    const float* b2    = (const float*)d_in[6];
    const float* Wfc   = (const float*)d_in[7];
    const float* bfc   = (const float*)d_in[8];
    float* out = (float*)d_out;

    const int* src = edge;       // edge_index[0]
    const int* dst = edge + E;   // edge_index[1]

    // workspace layout (1 KiB aligned regions), ~40 MB total
    char* base = (char*)d_ws;
    size_t o = 0;
    auto alloc = [&](size_t bytes) -> void* {
        void* p = base + o;
        o += (bytes + 1023) & ~size_t(1023);
        return p;
    };
    int*    cnt    = (int*)alloc((size_t)N * 4);
    float*  dinv   = (float*)alloc((size_t)N * 4);
    float2* gx     = (float2*)alloc((size_t)N * 8);
    float2* aggx   = (float2*)alloc((size_t)N * 8);
    int*    offs   = (int*)alloc((size_t)N * 4);
    int*    cursor = (int*)alloc((size_t)N * 4);
    int*    csr    = (int*)alloc((size_t)E * 4);
    float*  g2     = (float*)alloc((size_t)N * H * 4);
    float*  pooled = (float*)alloc((size_t)G * H * 4);
    int*    cntg   = (int*)alloc((size_t)G * 4);

    hipMemsetAsync(cnt, 0, (size_t)N * 4, stream);
    hipMemsetAsync(pooled, 0, (size_t)G * H * 4, stream);
    hipMemsetAsync(cntg, 0, (size_t)G * 4, stream);

    k_count<<<(E + 255) / 256, 256, 0, stream>>>(dst, cnt);
    k_dinv<<<(N + 255) / 256, 256, 0, stream>>>(x, cnt, dinv, gx);
    k_scan<<<1, 1024, 0, stream>>>(cnt, offs, cursor);
    k_fill<<<(E + 255) / 256, 256, 0, stream>>>(src, dst, cursor, csr);
    k_agg1<<<(N * 4 + 255) / 256, 256, 0, stream>>>(csr, offs, cnt, dinv, gx, aggx);
    k_mlp<<<1024, 256, 0, stream>>>(aggx, W1, b1, W2, dinv, g2);
    k_agg2<<<(N + 3) / 4, 256, 0, stream>>>(csr, offs, cnt, dinv, b2, g2, batch, pooled, cntg);
    k_final<<<G, 64, 0, stream>>>(pooled, cntg, Wfc, bfc, out);
}

// Round 2
// 1340.456 us; speedup vs baseline: 1.0714x; 1.0714x over previous
//
#include <hip/hip_runtime.h>

// Problem constants (match reference)
constexpr int N  = 100000;   // nodes
constexpr int E  = 3200000;  // edges
constexpr int G  = 128;      // graphs
constexpr int H  = 64;       // hidden

// ---------------------------------------------------------------------------
// K1: in-degree counts (dst occurrences); self-loop added later as +1
__global__ __launch_bounds__(256) void k_count(const int* __restrict__ dst,
                                               int* __restrict__ cnt) {
    int e = blockIdx.x * 256 + threadIdx.x;
    if (e < E) atomicAdd(&cnt[dst[e]], 1);
}

// K2: dinv = rsqrt(deg), gx = x * dinv (pre-scaled 2-channel features)
__global__ __launch_bounds__(256) void k_dinv(const float* __restrict__ x,
                                              const int* __restrict__ cnt,
                                              float* __restrict__ dinv,
                                              float2* __restrict__ gx) {
    int v = blockIdx.x * 256 + threadIdx.x;
    if (v < N) {
        float d = rsqrtf((float)(cnt[v] + 1));
        dinv[v] = d;
        float2 xv = ((const float2*)x)[v];
        gx[v] = make_float2(xv.x * d, xv.y * d);
    }
}

// K3: single-block exclusive scan of cnt -> offs (and cursor copy).
__global__ __launch_bounds__(1024) void k_scan(const int* __restrict__ cnt,
                                               int* __restrict__ offs,
                                               int* __restrict__ cursor) {
    constexpr int T = 1024;
    constexpr int PER = (N + T - 1) / T;  // 98
    int tid = threadIdx.x;
    int begin = tid * PER;
    int end = begin + PER; if (end > N) end = N;

    int total = 0;
    for (int i = begin; i < end; ++i) total += cnt[i];

    __shared__ int wsum[16];
    int lane = tid & 63, wid = tid >> 6;
    int incl = total;
    #pragma unroll
    for (int off = 1; off < 64; off <<= 1) {
        int t = __shfl_up(incl, off);
        if (lane >= off) incl += t;
    }
    if (lane == 63) wsum[wid] = incl;
    __syncthreads();
    if (wid == 0 && lane < 16) {
        int w = wsum[lane];
        #pragma unroll
        for (int off = 1; off < 16; off <<= 1) {
            int t = __shfl_up(w, off);
            if (lane >= off) w += t;
        }
        wsum[lane] = w;  // inclusive over waves
    }
    __syncthreads();
    int waveBase = (wid == 0) ? 0 : wsum[wid - 1];
    int run = waveBase + (incl - total);  // exclusive prefix of this thread
    for (int i = begin; i < end; ++i) {
        offs[i] = run;
        cursor[i] = run;
        run += cnt[i];
    }
}

// K4: fill CSR (src indices grouped by dst)
__global__ __launch_bounds__(256) void k_fill(const int* __restrict__ src,
                                              const int* __restrict__ dst,
                                              int* __restrict__ cursor,
                                              int* __restrict__ csr) {
    int e = blockIdx.x * 256 + threadIdx.x;
    if (e < E) {
        int d = dst[e];
        int pos = atomicAdd(&cursor[d], 1);
        csr[pos] = src[e];
    }
}

// K5: layer-1 aggregation in 2-channel input space. One wave per node,
// lane-per-edge: coalesced index load + 64 independent 8B gathers in flight.
__global__ __launch_bounds__(256) void k_agg1(const int* __restrict__ csr,
                                              const int* __restrict__ offs,
                                              const int* __restrict__ cnt,
                                              const float* __restrict__ dinv,
                                              const float2* __restrict__ gx,
                                              float2* __restrict__ aggx) {
    int lane = threadIdx.x & 63;
    int v = (blockIdx.x * 256 + threadIdx.x) >> 6;
    if (v >= N) return;
    int start = offs[v], dg = cnt[v];
    float ax = 0.f, ay = 0.f;
    for (int i = lane; i < dg; i += 64) {
        int s = csr[start + i];
        float2 g = gx[s];
        ax += g.x; ay += g.y;
    }
    #pragma unroll
    for (int off = 1; off < 64; off <<= 1) {
        ax += __shfl_xor(ax, off);
        ay += __shfl_xor(ay, off);
    }
    if (lane == 0) {
        float d = dinv[v];
        float2 g = gx[v];
        aggx[v] = make_float2(d * (ax + g.x), d * (ay + g.y));
    }
}

// K6: per-node MLP: t = relu(aggx @ W1 + b1); g2 = (t @ W2) * dinv[v]
__global__ __launch_bounds__(256) void k_mlp(const float2* __restrict__ aggx,
                                             const float* __restrict__ W1,
                                             const float* __restrict__ b1,
                                             const float* __restrict__ W2,
                                             const float* __restrict__ dinv,
                                             float* __restrict__ g2) {
    int lane = threadIdx.x & 63;
    int wave = (blockIdx.x * 256 + threadIdx.x) >> 6;
    int nw = gridDim.x * 4;

    float w2col[64];
    #pragma unroll
    for (int k = 0; k < 64; ++k) w2col[k] = W2[k * 64 + lane];
    float w10 = W1[lane], w11 = W1[64 + lane], bb = b1[lane];

    for (int v = wave; v < N; v += nw) {
        float2 a = aggx[v];
        float tt = fmaxf(fmaf(a.y, w11, fmaf(a.x, w10, bb)), 0.f);
        float a0 = 0.f, a1 = 0.f, a2 = 0.f, a3 = 0.f;
        #pragma unroll
        for (int k = 0; k < 64; k += 4) {
            float t0 = __int_as_float(__builtin_amdgcn_readlane(__float_as_int(tt), k + 0));
            float t1 = __int_as_float(__builtin_amdgcn_readlane(__float_as_int(tt), k + 1));
            float t2 = __int_as_float(__builtin_amdgcn_readlane(__float_as_int(tt), k + 2));
            float t3 = __int_as_float(__builtin_amdgcn_readlane(__float_as_int(tt), k + 3));
            a0 = fmaf(t0, w2col[k + 0], a0);
            a1 = fmaf(t1, w2col[k + 1], a1);
            a2 = fmaf(t2, w2col[k + 2], a2);
            a3 = fmaf(t3, w2col[k + 3], a3);
        }
        g2[(size_t)v * 64 + lane] = ((a0 + a1) + (a2 + a3)) * dinv[v];
    }
}

// K7: layer-2 aggregation (wave per node) + relu + fused mean-pool atomics.
// Indices preloaded 64-at-a-time with one coalesced load, broadcast via
// readlane (register-only) -> gather loop has no index-load dependency and
// 8 independent row loads in flight.
__global__ __launch_bounds__(256) void k_agg2(const int* __restrict__ csr,
                                              const int* __restrict__ offs,
                                              const int* __restrict__ cnt,
                                              const float* __restrict__ dinv,
                                              const float* __restrict__ b2,
                                              const float* __restrict__ g2,
                                              const int* __restrict__ batch,
                                              float* __restrict__ pooled,
                                              int* __restrict__ cntg) {
    int lane = threadIdx.x & 63;
    int v = (blockIdx.x * 256 + threadIdx.x) >> 6;
    if (v >= N) return;
    int start = offs[v], dg = cnt[v];
    float acc = g2[(size_t)v * 64 + lane];  // self-loop term

    int base = 0;
    while (base < dg) {
        int chunk = dg - base; if (chunk > 64) chunk = 64;
        // one coalesced index load covers the whole chunk (csr padded-read ok:
        // region is followed by more workspace)
        int idx = csr[start + base + lane];
        int i = 0;
        for (; i + 8 <= chunk; i += 8) {
            const float* r0 = g2 + (size_t)__builtin_amdgcn_readlane(idx, i + 0) * 64;
            const float* r1 = g2 + (size_t)__builtin_amdgcn_readlane(idx, i + 1) * 64;
            const float* r2 = g2 + (size_t)__builtin_amdgcn_readlane(idx, i + 2) * 64;
            const float* r3 = g2 + (size_t)__builtin_amdgcn_readlane(idx, i + 3) * 64;
            const float* r4 = g2 + (size_t)__builtin_amdgcn_readlane(idx, i + 4) * 64;
            const float* r5 = g2 + (size_t)__builtin_amdgcn_readlane(idx, i + 5) * 64;
            const float* r6 = g2 + (size_t)__builtin_amdgcn_readlane(idx, i + 6) * 64;
            const float* r7 = g2 + (size_t)__builtin_amdgcn_readlane(idx, i + 7) * 64;
            float f0 = r0[lane], f1 = r1[lane], f2 = r2[lane], f3 = r3[lane];
            float f4 = r4[lane], f5 = r5[lane], f6 = r6[lane], f7 = r7[lane];
            acc += ((f0 + f1) + (f2 + f3)) + ((f4 + f5) + (f6 + f7));
        }
        for (; i < chunk; ++i) {
            const float* r = g2 + (size_t)__builtin_amdgcn_readlane(idx, i) * 64;
            acc += r[lane];
        }
        base += chunk;
    }

    float o = fmaxf(fmaf(dinv[v], acc, b2[lane]), 0.f);
    int b = batch[v];
    atomicAdd(&pooled[b * 64 + lane], o);
    if (lane == 0) atomicAdd(&cntg[b], 1);
}

// K8: final: out[g] = (pooled[g]/max(cnt,1)) . Wfc + bfc
__global__ __launch_bounds__(64) void k_final(const float* __restrict__ pooled,
                                              const int* __restrict__ cntg,
                                              const float* __restrict__ Wfc,
                                              const float* __restrict__ bfc,
                                              float* __restrict__ out) {
    int g = blockIdx.x;
    int j = threadIdx.x;  // 64
    float c = fmaxf((float)cntg[g], 1.f);
    float p = (pooled[g * 64 + j] / c) * Wfc[j];
    #pragma unroll
    for (int off = 32; off >= 1; off >>= 1) p += __shfl_down(p, off);
    if (j == 0) out[g] = p + bfc[0];
}

// ---------------------------------------------------------------------------
extern "C" void kernel_launch(void* const* d_in, const int* in_sizes, int n_in,
                              void* d_out, int out_size, void* d_ws, size_t ws_size,
                              hipStream_t stream) {
    const float* x     = (const float*)d_in[0];
    const int*   edge  = (const int*)d_in[1];
    const int*   batch = (const int*)d_in[2];
    const float* W1    = (const float*)d_in[3];
    const float* b1    = (const float*)d_in[4];
    const float* W2    = (const float*)d_in[5];
    const float* b2    = (const float*)d_in[6];
    const float* Wfc   = (const float*)d_in[7];
    const float* bfc   = (const float*)d_in[8];
    float* out = (float*)d_out;

    const int* src = edge;       // edge_index[0]
    const int* dst = edge + E;   // edge_index[1]

    // workspace layout (1 KiB aligned regions), ~40 MB total
    char* base = (char*)d_ws;
    size_t o = 0;
    auto alloc = [&](size_t bytes) -> void* {
        void* p = base + o;
        o += (bytes + 1023) & ~size_t(1023);
        return p;
    };
    int*    cnt    = (int*)alloc((size_t)N * 4);
    float*  dinv   = (float*)alloc((size_t)N * 4);
    float2* gx     = (float2*)alloc((size_t)N * 8);
    float2* aggx   = (float2*)alloc((size_t)N * 8);
    int*    offs   = (int*)alloc((size_t)N * 4);
    int*    cursor = (int*)alloc((size_t)N * 4);
    int*    csr    = (int*)alloc((size_t)E * 4 + 1024);  // +pad for 64-lane over-read
    float*  g2     = (float*)alloc((size_t)N * H * 4);
    float*  pooled = (float*)alloc((size_t)G * H * 4);
    int*    cntg   = (int*)alloc((size_t)G * 4);

    hipMemsetAsync(cnt, 0, (size_t)N * 4, stream);
    hipMemsetAsync(pooled, 0, (size_t)G * H * 4, stream);
    hipMemsetAsync(cntg, 0, (size_t)G * 4, stream);

    k_count<<<(E + 255) / 256, 256, 0, stream>>>(dst, cnt);
    k_dinv<<<(N + 255) / 256, 256, 0, stream>>>(x, cnt, dinv, gx);
    k_scan<<<1, 1024, 0, stream>>>(cnt, offs, cursor);
    k_fill<<<(E + 255) / 256, 256, 0, stream>>>(src, dst, cursor, csr);
    k_agg1<<<(N + 3) / 4, 256, 0, stream>>>(csr, offs, cnt, dinv, gx, aggx);
    k_mlp<<<1024, 256, 0, stream>>>(aggx, W1, b1, W2, dinv, g2);
    k_agg2<<<(N + 3) / 4, 256, 0, stream>>>(csr, offs, cnt, dinv, b2, g2, batch, pooled, cntg);
    k_final<<<G, 64, 0, stream>>>(pooled, cntg, Wfc, bfc, out);
}